// Round 21
// baseline (212.677 us; speedup 1.0000x reference)
//
#include <hip/hip_runtime.h>
#include <hip/hip_bf16.h>
#include <stdint.h>

namespace {

constexpr int Bx = 4, Tx = 2048, Cx = 1024, Hx = 16, Dx = 64;
constexpr int Mx = Bx * Tx;  // 8192

typedef __attribute__((ext_vector_type(8))) short bf16x8;
typedef __attribute__((ext_vector_type(4))) float f32x4;
typedef __attribute__((ext_vector_type(16))) float f32x16;
typedef __attribute__((ext_vector_type(2))) unsigned int u32x2;

__device__ __forceinline__ float b2f(unsigned short u) {
  unsigned int v = ((unsigned int)u) << 16;
  return __builtin_bit_cast(float, v);
}
__device__ __forceinline__ unsigned short f2b(float f) {
  unsigned int v = __builtin_bit_cast(unsigned int, f);
  v += 0x7fffu + ((v >> 16) & 1u);
  return (unsigned short)(v >> 16);
}
__device__ __forceinline__ uint32_t pkbf(float a, float b) {
  __hip_bfloat162 h = __float22bfloat162_rn(float2{a, b});
  uint32_t r;
  __builtin_memcpy(&r, &h, 4);  // __hip_bfloat162 not trivially copyable -> no bit_cast
  return r;
}
// permlane32_swap via builtin (compiler handles VALU->permlane hazards):
//   a_new[i] = i<32 ? a[i] : b[i-32];  b_new[i] = i<32 ? a[i+32] : b[i]
__device__ __forceinline__ void pl32swap(uint32_t& a, uint32_t& b) {
  u32x2 r = __builtin_amdgcn_permlane32_swap(a, b, false, false);
  a = r[0];
  b = r[1];
}

#define GLD16(g, lp) __builtin_amdgcn_global_load_lds(                     \
    (__attribute__((address_space(1))) void*)(g),                          \
    (__attribute__((address_space(3))) void*)(lp), 16, 0, 0)

// ---------------- convert fp32 -> bf16 (vectorized) ----------------
__global__ void ca_cvt(const float* __restrict__ src, unsigned short* __restrict__ dst, int n4) {
  int i = blockIdx.x * blockDim.x + threadIdx.x;
  int stride = gridDim.x * blockDim.x;
  for (; i < n4; i += stride) {
    float4 f = ((const float4*)src)[i];
    ushort4 o;
    o.x = f2b(f.x); o.y = f2b(f.y); o.z = f2b(f.z); o.w = f2b(f.w);
    ((ushort4*)dst)[i] = o;
  }
}

// ---------------- 4x W (K x N) -> Wt (N x K) bf16, one launch ---------------
__global__ void ca_wt4(const float* __restrict__ W0, const float* __restrict__ W1,
                       const float* __restrict__ W2, const float* __restrict__ W3,
                       unsigned short* __restrict__ Wt) {
  __shared__ float tile[32][33];
  int z = blockIdx.z;
  const float* W = z == 0 ? W0 : (z == 1 ? W1 : (z == 2 ? W2 : W3));
  unsigned short* o = Wt + (size_t)z * Cx * Cx;
  int n0 = blockIdx.x * 32, k0 = blockIdx.y * 32;
  int j = threadIdx.x & 31, i = threadIdx.x >> 5;  // i in 0..7
#pragma unroll
  for (int r = 0; r < 4; ++r)
    tile[i + 8 * r][j] = W[(size_t)(k0 + i + 8 * r) * Cx + n0 + j];
  __syncthreads();
#pragma unroll
  for (int r = 0; r < 4; ++r)
    o[(size_t)(n0 + i + 8 * r) * Cx + k0 + j] = f2b(tile[j][i + 8 * r]);
}

// ---------------- RoPE cos/sin table ----------------
__global__ void ca_rtab(float* __restrict__ ct, float* __restrict__ st) {
  int idx = blockIdx.x * blockDim.x + threadIdx.x;  // < Tx*32
  int t = idx >> 5, i = idx & 31;
  float fr = expf((float)i * -0.29710775393471563f);  // -ln(10000)/31
  float a = (float)t * fr;
  ct[idx] = cosf(a);
  st[idx] = sinf(a);
}

// ---------------- GEMM: A (MxK bf16) x Bt (NxK bf16) + bias ----------------
// r21: quad-buffer + counted-vmcnt pipeline. Old 2-phase used __syncthreads
// (vmcnt(0) drain) right after issuing the prefetch -> every iter serialized a
// full L2 round-trip. Now: stage kt+2 (2 iters of slack), wait vmcnt(8) (only
// the tile about to be read), ONE raw s_barrier/iter -- prefetch loads stay in
// flight across barriers (T4). LDS 4x(8+8)KB = 64KB -> 2 blocks/CU unchanged.
// MODE 0 epilogue: q row-major + k,v direct to fragment-linear + fused RoPE.
template <int MODE>
__global__ __launch_bounds__(256) void ca_gemm(
    const unsigned short* __restrict__ A, const unsigned short* __restrict__ Bt,
    const float* __restrict__ b0, const float* __restrict__ b1, const float* __restrict__ b2,
    const float* __restrict__ ctab, const float* __restrict__ stab,
    void* __restrict__ out, unsigned short* __restrict__ kfl, unsigned short* __restrict__ vfl,
    int M, int N, int K) {
  __shared__ __align__(16) unsigned short Al[4][128 * 32];
  __shared__ __align__(16) unsigned short Bl[4][128 * 32];
  int tid = threadIdx.x;
  int w = tid >> 6, l = tid & 63;
  int m0 = blockIdx.x * 128, n0 = blockIdx.y * 128;  // m-fast (r16 order)
  int wm = (w >> 1) * 64, wn = (w & 1) * 64;
  f32x4 acc[4][4] = {};

  int lr = l & 15, lk8 = (l >> 4) * 8;
  int srow = w * 32 + (l >> 2), scol = (l & 3) * 8;
  const unsigned short* ga0 = A + (size_t)(m0 + srow) * K + scol;
  const unsigned short* gb0 = Bt + (size_t)(n0 + srow) * K + scol;
  int nk = K / 32;
  auto stage = [&](int kt, int buf) {
    const unsigned short* ga = ga0 + kt * 32;
    const unsigned short* gb = gb0 + kt * 32;
    unsigned short* la = &Al[buf][w * 1024];
    unsigned short* lb = &Bl[buf][w * 1024];
    GLD16(ga, la);
    GLD16(ga + (size_t)16 * K, la + 512);
    GLD16(gb, lb);
    GLD16(gb + (size_t)16 * K, lb + 512);
  };
  stage(0, 0);
  stage(1, 1);
  for (int kt = 0; kt < nk; ++kt) {
    int cur = kt & 3;
    if (kt + 2 < nk) stage(kt + 2, (kt + 2) & 3);  // 2-deep prefetch
    // wait ONLY for kt's 4 loads (oldest); newer stages stay in flight
    int ahead = nk - 1 - kt;
    if (ahead >= 2) {
      asm volatile("s_waitcnt vmcnt(8)" ::: "memory");
    } else if (ahead == 1) {
      asm volatile("s_waitcnt vmcnt(4)" ::: "memory");
    } else {
      asm volatile("s_waitcnt vmcnt(0)" ::: "memory");
    }
    __builtin_amdgcn_sched_barrier(0);
    __builtin_amdgcn_s_barrier();  // all waves' kt data landed; reads of the
                                   // buffer being re-staged finished >=2 bars ago
    bf16x8 af[4], bfr[4];
#pragma unroll
    for (int mi = 0; mi < 4; ++mi)
      af[mi] = *(const bf16x8*)&Al[cur][(wm + mi * 16 + lr) * 32 + lk8];
#pragma unroll
    for (int ni = 0; ni < 4; ++ni)
      bfr[ni] = *(const bf16x8*)&Bl[cur][(wn + ni * 16 + lr) * 32 + lk8];
#pragma unroll
    for (int mi = 0; mi < 4; ++mi)
#pragma unroll
      for (int ni = 0; ni < 4; ++ni)
        acc[mi][ni] = __builtin_amdgcn_mfma_f32_16x16x32_bf16(af[mi], bfr[ni], acc[mi][ni], 0, 0, 0);
  }

  int lq4 = (l >> 4) * 4;
  if (MODE == 0) {
    constexpr float SC = 0.18033688011112042f;  // 0.125 * log2(e)
    int which = n0 >> 10;
    int nb = n0 & 1023;
    const float* bias = which == 0 ? b0 : (which == 1 ? b1 : b2);
    unsigned short* o = (unsigned short*)out;  // q only
    bool doRope = which < 2;
    float scl = which == 0 ? SC : 1.0f;
#pragma unroll
    for (int mi = 0; mi < 4; ++mi)
#pragma unroll
      for (int ni = 0; ni < 4; ++ni) {
        int ncol = nb + wn + ni * 16 + lr;
        float bv = bias[ncol];
        int j = (ncol & 63) >> 1;
        bool even = (ncol & 1) == 0;
        int h = ncol >> 6, d = ncol & 63;
        int m_base = m0 + wm + mi * 16 + lq4;
        float vals[4];
#pragma unroll
        for (int rg = 0; rg < 4; ++rg) {
          int m = m_base + rg;
          float val = acc[mi][ni][rg] + bv;
          if (doRope) {
            int t = m & (Tx - 1);
            float c = ctab[t * 32 + j], s = stab[t * 32 + j];
            float other = __shfl_xor(val, 1);
            float res = even ? (val * c - other * s) : (other * s + val * c);
            val = res * scl;
          }
          vals[rg] = val;
        }
        if (which == 0) {
#pragma unroll
          for (int rg = 0; rg < 4; ++rg)
            o[(size_t)(m_base + rg) * 1024 + ncol] = f2b(vals[rg]);
        } else if (which == 1) {
          // k -> fragment-linear: [bh][t>>5][d>>4][((d>>3)&1)*32+(t&31)]*8+(d&7)
          int bh = (m_base >> 11) * 16 + h;
          size_t tilebase = ((size_t)bh * 64) * 2048 + (d >> 4) * 512 + (((d >> 3) & 1) * 32) * 8 + (d & 7);
#pragma unroll
          for (int rg = 0; rg < 4; ++rg) {
            int t = (m_base + rg) & (Tx - 1);
            kfl[tilebase + (size_t)(t >> 5) * 2048 + (t & 31) * 8] = f2b(vals[rg]);
          }
        } else {
          // v -> fragment-linear: rg-consecutive t => consecutive e: one 8B store
          int t = m_base & (Tx - 1);
          int bh = (m_base >> 11) * 16 + h;
          int tin = t & 31;
          size_t base = ((size_t)bh * 64 + (t >> 5)) * 2048 +
                        ((d >> 5) * 2 + ((tin >> 4) & 1)) * 512 +
                        (((tin >> 3) & 1) * 32 + (d & 31)) * 8 + (tin & 7);
          ushort4 pk4;
          pk4.x = f2b(vals[0]); pk4.y = f2b(vals[1]);
          pk4.z = f2b(vals[2]); pk4.w = f2b(vals[3]);
          *(ushort4*)(vfl + base) = pk4;
        }
      }
  } else {
    float* o = (float*)out;
#pragma unroll
    for (int mi = 0; mi < 4; ++mi)
#pragma unroll
      for (int ni = 0; ni < 4; ++ni) {
        int ncol = n0 + wn + ni * 16 + lr;
        float bv = b0[ncol];
#pragma unroll
        for (int rg = 0; rg < 4; ++rg) {
          int m = m0 + wm + mi * 16 + lq4 + rg;
          o[(size_t)m * N + ncol] = acc[mi][ni][rg] + bv;
        }
      }
  }
}

// ---------------- causal flash attention (r14 structure) --------------------
__global__ __launch_bounds__(64) void ca_attn(
    const unsigned short* __restrict__ q, const unsigned short* __restrict__ kfl,
    const unsigned short* __restrict__ vfl, unsigned short* __restrict__ y) {
  __shared__ uint32_t els[32][33];
  int l = threadIdx.x & 63;
  int bh = blockIdx.x;                              // XCD = id%8 = bh%8 -> KV L2-pinned
  int qt = (int)gridDim.y - 1 - (int)blockIdx.y;    // heavy q-tiles first
  int b = bh >> 4, h16 = bh & 15;
  const unsigned short* qp = q + (size_t)b * Tx * Cx + h16 * Dx;
  const unsigned short* kb = kfl + (size_t)bh * 64 * 2048 + l * 8;
  const unsigned short* vb = vfl + (size_t)bh * 64 * 2048 + l * 8;
  int lo = l & 31, hi = l >> 5;
  constexpr float SHIFT = 20.0f;  // static softmax shift (log2 domain)
  const uint32_t one2 = 0x3F803F80u;  // bf16 1.0 x2
  uint4 onesw{one2, one2, one2, one2};
  bf16x8 ONES = __builtin_bit_cast(bf16x8, onesw);

  int qbase = qt * 32;

  bf16x8 qf[4];
  {
    const unsigned short* qr = qp + (size_t)(qbase + lo) * Cx + hi * 8;
#pragma unroll
    for (int c = 0; c < 4; ++c) qf[c] = *(const bf16x8*)(qr + c * 16);
  }

  f32x16 acc0 = {}, acc1 = {}, sacc = {};
  int nt = qt + 1;

  uint4 rk[4], rv[4];
  auto loadK = [&](int t) {
#pragma unroll
    for (int c = 0; c < 4; ++c) rk[c] = *(const uint4*)(kb + t * 2048 + c * 512);
  };
  auto loadV = [&](int t) {
#pragma unroll
    for (int j = 0; j < 4; ++j) rv[j] = *(const uint4*)(vb + t * 2048 + j * 512);
  };
  loadK(0);
  loadV(0);

  for (int t = 0; t < nt; ++t) {
    bf16x8 kf[4], vf[4];
#pragma unroll
    for (int c = 0; c < 4; ++c) kf[c] = __builtin_bit_cast(bf16x8, rk[c]);
#pragma unroll
    for (int c = 0; c < 4; ++c) vf[c] = __builtin_bit_cast(bf16x8, rv[c]);
    if (t + 1 < nt) { loadK(t + 1); loadV(t + 1); }  // prefetch under softmax

    __builtin_amdgcn_s_setprio(1);
    f32x16 s = {};
    s = __builtin_amdgcn_mfma_f32_32x32x16_bf16(kf[0], qf[0], s, 0, 0, 0);
    s = __builtin_amdgcn_mfma_f32_32x32x16_bf16(kf[1], qf[1], s, 0, 0, 0);
    s = __builtin_amdgcn_mfma_f32_32x32x16_bf16(kf[2], qf[2], s, 0, 0, 0);
    s = __builtin_amdgcn_mfma_f32_32x32x16_bf16(kf[3], qf[3], s, 0, 0, 0);
    __builtin_amdgcn_s_setprio(0);

    float p[16];
    if (t == nt - 1) {  // diagonal tile is exactly the last tile
#pragma unroll
      for (int r = 0; r < 16; ++r) {
        int kvr = (r & 3) + 8 * (r >> 2) + 4 * hi;
        p[r] = (kvr > lo) ? 0.f : exp2f(s[r] - SHIFT);
      }
    } else {
#pragma unroll
      for (int r = 0; r < 16; ++r) p[r] = exp2f(s[r] - SHIFT);
    }

    uint32_t pk[8];
#pragma unroll
    for (int i = 0; i < 8; ++i) pk[i] = pkbf(p[2 * i], p[2 * i + 1]);
    pl32swap(pk[0], pk[2]);
    pl32swap(pk[1], pk[3]);
    pl32swap(pk[4], pk[6]);
    pl32swap(pk[5], pk[7]);
    uint4 xw{pk[0], pk[1], pk[2], pk[3]}, yw{pk[4], pk[5], pk[6], pk[7]};
    bf16x8 PB0 = __builtin_bit_cast(bf16x8, xw);
    bf16x8 PB1 = __builtin_bit_cast(bf16x8, yw);
    __builtin_amdgcn_s_setprio(1);
    acc0 = __builtin_amdgcn_mfma_f32_32x32x16_bf16(vf[0], PB0, acc0, 0, 0, 0);
    acc1 = __builtin_amdgcn_mfma_f32_32x32x16_bf16(vf[2], PB0, acc1, 0, 0, 0);
    sacc = __builtin_amdgcn_mfma_f32_32x32x16_bf16(ONES, PB0, sacc, 0, 0, 0);
    acc0 = __builtin_amdgcn_mfma_f32_32x32x16_bf16(vf[1], PB1, acc0, 0, 0, 0);
    acc1 = __builtin_amdgcn_mfma_f32_32x32x16_bf16(vf[3], PB1, acc1, 0, 0, 0);
    sacc = __builtin_amdgcn_mfma_f32_32x32x16_bf16(ONES, PB1, sacc, 0, 0, 0);
    __builtin_amdgcn_s_setprio(0);
  }

  float rl = __builtin_amdgcn_rcpf(sacc[0]);  // lsum for this lane's q-col
#pragma unroll
  for (int dc = 0; dc < 2; ++dc) {
    f32x16 a = dc ? acc1 : acc0;
#pragma unroll
    for (int i = 0; i < 8; ++i) {
      uint32_t pkd = pkbf(a[2 * i] * rl, a[2 * i + 1] * rl);
      int d2 = (i & 1) + 4 * (i >> 1) + 2 * hi + dc * 16;
      els[lo][d2] = pkd;
    }
  }
  __syncthreads();
  unsigned short* yp = y + (size_t)b * Tx * Cx + h16 * Dx;
#pragma unroll
  for (int pp = 0; pp < 16; ++pp) {
    int qr = 2 * pp + hi;
    uint32_t val = els[qr][lo];
    *(uint32_t*)(yp + (size_t)(qbase + qr) * Cx + lo * 2) = val;
  }
}

}  // namespace

extern "C" void kernel_launch(void* const* d_in, const int* in_sizes, int n_in,
                              void* d_out, int out_size, void* d_ws, size_t ws_size,
                              hipStream_t stream) {
  const float* x = (const float*)d_in[0];
  const float* Wq = (const float*)d_in[1];
  const float* bq = (const float*)d_in[2];
  const float* Wk = (const float*)d_in[3];
  const float* bk = (const float*)d_in[4];
  const float* Wv = (const float*)d_in[5];
  const float* bv = (const float*)d_in[6];
  const float* Wp = (const float*)d_in[7];
  const float* bp = (const float*)d_in[8];

  unsigned short* xb = (unsigned short*)d_ws;                 // 8192*1024
  unsigned short* wt = xb + (size_t)Mx * Cx;                  // 4 * 1024*1024 (WqT,WkT,WvT,WpT)
  float* ct = (float*)(wt + (size_t)4 * Cx * Cx);             // 2048*32
  float* st = ct + Tx * 32;
  unsigned short* qb = (unsigned short*)(st + Tx * 32);       // q (gemm0 out)
  unsigned short* yb = qb + (size_t)Mx * Cx;                  // attn out
  unsigned short* kfl = yb + (size_t)Mx * Cx;                 // 64*64*2048 = 8M ushort
  unsigned short* vfl = kfl + (size_t)64 * 64 * 2048;

  ca_cvt<<<dim3(2048), dim3(256), 0, stream>>>(x, xb, Mx * Cx / 4);
  ca_wt4<<<dim3(32, 32, 4), dim3(256), 0, stream>>>(Wq, Wk, Wv, Wp, wt);
  ca_rtab<<<dim3(Tx * 32 / 256), dim3(256), 0, stream>>>(ct, st);

  ca_gemm<0><<<dim3(64, 24), dim3(256), 0, stream>>>(
      /*A=*/xb, /*Bt=*/wt, /*b0=*/bq, /*b1=*/bk, /*b2=*/bv,
      /*ctab=*/ct, /*stab=*/st, /*out=*/qb, /*kfl=*/kfl, /*vfl=*/vfl,
      /*M=*/Mx, /*N=*/3072, /*K=*/Cx);
  ca_attn<<<dim3(64, 64), dim3(64), 0, stream>>>(qb, kfl, vfl, yb);
  ca_gemm<1><<<dim3(64, 8), dim3(256), 0, stream>>>(
      /*A=*/yb, /*Bt=*/wt + (size_t)3 * Cx * Cx, /*b0=*/bp, /*b1=*/nullptr, /*b2=*/nullptr,
      /*ctab=*/nullptr, /*stab=*/nullptr, /*out=*/d_out, /*kfl=*/nullptr, /*vfl=*/nullptr,
      /*M=*/Mx, /*N=*/Cx, /*K=*/Cx);
}

// Round 22
// 204.770 us; speedup vs baseline: 1.0386x; 1.0386x over previous
//
#include <hip/hip_runtime.h>
#include <hip/hip_bf16.h>
#include <stdint.h>

namespace {

constexpr int Bx = 4, Tx = 2048, Cx = 1024, Hx = 16, Dx = 64;
constexpr int Mx = Bx * Tx;  // 8192

typedef __attribute__((ext_vector_type(8))) short bf16x8;
typedef __attribute__((ext_vector_type(4))) float f32x4;
typedef __attribute__((ext_vector_type(16))) float f32x16;
typedef __attribute__((ext_vector_type(2))) unsigned int u32x2;

__device__ __forceinline__ float b2f(unsigned short u) {
  unsigned int v = ((unsigned int)u) << 16;
  return __builtin_bit_cast(float, v);
}
__device__ __forceinline__ unsigned short f2b(float f) {
  unsigned int v = __builtin_bit_cast(unsigned int, f);
  v += 0x7fffu + ((v >> 16) & 1u);
  return (unsigned short)(v >> 16);
}
__device__ __forceinline__ uint32_t pkbf(float a, float b) {
  __hip_bfloat162 h = __float22bfloat162_rn(float2{a, b});
  uint32_t r;
  __builtin_memcpy(&r, &h, 4);  // __hip_bfloat162 not trivially copyable -> no bit_cast
  return r;
}
// permlane32_swap via builtin (compiler handles VALU->permlane hazards):
//   a_new[i] = i<32 ? a[i] : b[i-32];  b_new[i] = i<32 ? a[i+32] : b[i]
__device__ __forceinline__ void pl32swap(uint32_t& a, uint32_t& b) {
  u32x2 r = __builtin_amdgcn_permlane32_swap(a, b, false, false);
  a = r[0];
  b = r[1];
}

#define GLD16(g, lp) __builtin_amdgcn_global_load_lds(                     \
    (__attribute__((address_space(1))) void*)(g),                          \
    (__attribute__((address_space(3))) void*)(lp), 16, 0, 0)

// ---------------- convert fp32 -> bf16 (vectorized) ----------------
__global__ void ca_cvt(const float* __restrict__ src, unsigned short* __restrict__ dst, int n4) {
  int i = blockIdx.x * blockDim.x + threadIdx.x;
  int stride = gridDim.x * blockDim.x;
  for (; i < n4; i += stride) {
    float4 f = ((const float4*)src)[i];
    ushort4 o;
    o.x = f2b(f.x); o.y = f2b(f.y); o.z = f2b(f.z); o.w = f2b(f.w);
    ((ushort4*)dst)[i] = o;
  }
}

// ---------------- 4x W (K x N) -> Wt (N x K) bf16, one launch ---------------
__global__ void ca_wt4(const float* __restrict__ W0, const float* __restrict__ W1,
                       const float* __restrict__ W2, const float* __restrict__ W3,
                       unsigned short* __restrict__ Wt) {
  __shared__ float tile[32][33];
  int z = blockIdx.z;
  const float* W = z == 0 ? W0 : (z == 1 ? W1 : (z == 2 ? W2 : W3));
  unsigned short* o = Wt + (size_t)z * Cx * Cx;
  int n0 = blockIdx.x * 32, k0 = blockIdx.y * 32;
  int j = threadIdx.x & 31, i = threadIdx.x >> 5;  // i in 0..7
#pragma unroll
  for (int r = 0; r < 4; ++r)
    tile[i + 8 * r][j] = W[(size_t)(k0 + i + 8 * r) * Cx + n0 + j];
  __syncthreads();
#pragma unroll
  for (int r = 0; r < 4; ++r)
    o[(size_t)(n0 + i + 8 * r) * Cx + k0 + j] = f2b(tile[j][i + 8 * r]);
}

// ---------------- RoPE cos/sin table ----------------
__global__ void ca_rtab(float* __restrict__ ct, float* __restrict__ st) {
  int idx = blockIdx.x * blockDim.x + threadIdx.x;  // < Tx*32
  int t = idx >> 5, i = idx & 31;
  float fr = expf((float)i * -0.29710775393471563f);  // -ln(10000)/31
  float a = (float)t * fr;
  ct[idx] = cosf(a);
  st[idx] = sinf(a);
}

// ---------------- GEMM: A (MxK bf16) x Bt (NxK bf16) + bias ----------------
// r20 configuration RESTORED (measured 205.1us total; r21 quad-buffer +
// counted-vmcnt regressed to 98.4us on gemm0: 64KB LDS halved residency,
// FETCH +8MB -- third confirmation with r15/m131-141 that the 2-phase +
// inter-block-overlap structure is this shape's practical optimum).
// MODE 0 epilogue: q row-major + k,v direct to fragment-linear + fused RoPE.
template <int MODE>
__global__ __launch_bounds__(256) void ca_gemm(
    const unsigned short* __restrict__ A, const unsigned short* __restrict__ Bt,
    const float* __restrict__ b0, const float* __restrict__ b1, const float* __restrict__ b2,
    const float* __restrict__ ctab, const float* __restrict__ stab,
    void* __restrict__ out, unsigned short* __restrict__ kfl, unsigned short* __restrict__ vfl,
    int M, int N, int K) {
  __shared__ __align__(16) unsigned short Al[2][128 * 32];
  __shared__ __align__(16) unsigned short Bl[2][128 * 32];
  int tid = threadIdx.x;
  int w = tid >> 6, l = tid & 63;
  int m0 = blockIdx.x * 128, n0 = blockIdx.y * 128;  // m-fast (r16 order)
  int wm = (w >> 1) * 64, wn = (w & 1) * 64;
  f32x4 acc[4][4] = {};

  int lr = l & 15, lk8 = (l >> 4) * 8;
  int srow = w * 32 + (l >> 2), scol = (l & 3) * 8;
  const unsigned short* ga0 = A + (size_t)(m0 + srow) * K + scol;
  const unsigned short* gb0 = Bt + (size_t)(n0 + srow) * K + scol;
  int nk = K / 32;
  auto stage = [&](int kt, int buf) {
    const unsigned short* ga = ga0 + kt * 32;
    const unsigned short* gb = gb0 + kt * 32;
    unsigned short* la = &Al[buf][w * 1024];
    unsigned short* lb = &Bl[buf][w * 1024];
    GLD16(ga, la);
    GLD16(ga + (size_t)16 * K, la + 512);
    GLD16(gb, lb);
    GLD16(gb + (size_t)16 * K, lb + 512);
  };
  stage(0, 0);
  __syncthreads();  // buf0 ready
  int cur = 0;
  for (int kt = 0; kt < nk; ++kt) {
    if (kt + 1 < nk) stage(kt + 1, cur ^ 1);  // in flight under compute
    bf16x8 af[4], bfr[4];
#pragma unroll
    for (int mi = 0; mi < 4; ++mi)
      af[mi] = *(const bf16x8*)&Al[cur][(wm + mi * 16 + lr) * 32 + lk8];
#pragma unroll
    for (int ni = 0; ni < 4; ++ni)
      bfr[ni] = *(const bf16x8*)&Bl[cur][(wn + ni * 16 + lr) * 32 + lk8];
#pragma unroll
    for (int mi = 0; mi < 4; ++mi)
#pragma unroll
      for (int ni = 0; ni < 4; ++ni)
        acc[mi][ni] = __builtin_amdgcn_mfma_f32_16x16x32_bf16(af[mi], bfr[ni], acc[mi][ni], 0, 0, 0);
    __syncthreads();  // drains stage (vmcnt0) + all waves done reading cur
    cur ^= 1;
  }

  int lq4 = (l >> 4) * 4;
  if (MODE == 0) {
    constexpr float SC = 0.18033688011112042f;  // 0.125 * log2(e)
    int which = n0 >> 10;
    int nb = n0 & 1023;
    const float* bias = which == 0 ? b0 : (which == 1 ? b1 : b2);
    unsigned short* o = (unsigned short*)out;  // q only
    bool doRope = which < 2;
    float scl = which == 0 ? SC : 1.0f;
#pragma unroll
    for (int mi = 0; mi < 4; ++mi)
#pragma unroll
      for (int ni = 0; ni < 4; ++ni) {
        int ncol = nb + wn + ni * 16 + lr;
        float bv = bias[ncol];
        int j = (ncol & 63) >> 1;
        bool even = (ncol & 1) == 0;
        int h = ncol >> 6, d = ncol & 63;
        int m_base = m0 + wm + mi * 16 + lq4;
        float vals[4];
#pragma unroll
        for (int rg = 0; rg < 4; ++rg) {
          int m = m_base + rg;
          float val = acc[mi][ni][rg] + bv;
          if (doRope) {
            int t = m & (Tx - 1);
            float c = ctab[t * 32 + j], s = stab[t * 32 + j];
            float other = __shfl_xor(val, 1);
            float res = even ? (val * c - other * s) : (other * s + val * c);
            val = res * scl;
          }
          vals[rg] = val;
        }
        if (which == 0) {
#pragma unroll
          for (int rg = 0; rg < 4; ++rg)
            o[(size_t)(m_base + rg) * 1024 + ncol] = f2b(vals[rg]);
        } else if (which == 1) {
          // k -> fragment-linear: [bh][t>>5][d>>4][((d>>3)&1)*32+(t&31)]*8+(d&7)
          int bh = (m_base >> 11) * 16 + h;
          size_t tilebase = ((size_t)bh * 64) * 2048 + (d >> 4) * 512 + (((d >> 3) & 1) * 32) * 8 + (d & 7);
#pragma unroll
          for (int rg = 0; rg < 4; ++rg) {
            int t = (m_base + rg) & (Tx - 1);
            kfl[tilebase + (size_t)(t >> 5) * 2048 + (t & 31) * 8] = f2b(vals[rg]);
          }
        } else {
          // v -> fragment-linear: rg-consecutive t => consecutive e: one 8B store
          int t = m_base & (Tx - 1);
          int bh = (m_base >> 11) * 16 + h;
          int tin = t & 31;
          size_t base = ((size_t)bh * 64 + (t >> 5)) * 2048 +
                        ((d >> 5) * 2 + ((tin >> 4) & 1)) * 512 +
                        (((tin >> 3) & 1) * 32 + (d & 31)) * 8 + (tin & 7);
          ushort4 pk4;
          pk4.x = f2b(vals[0]); pk4.y = f2b(vals[1]);
          pk4.z = f2b(vals[2]); pk4.w = f2b(vals[3]);
          *(ushort4*)(vfl + base) = pk4;
        }
      }
  } else {
    float* o = (float*)out;
#pragma unroll
    for (int mi = 0; mi < 4; ++mi)
#pragma unroll
      for (int ni = 0; ni < 4; ++ni) {
        int ncol = n0 + wn + ni * 16 + lr;
        float bv = b0[ncol];
#pragma unroll
        for (int rg = 0; rg < 4; ++rg) {
          int m = m0 + wm + mi * 16 + lq4 + rg;
          o[(size_t)m * N + ncol] = acc[mi][ni][rg] + bv;
        }
      }
  }
}

// ---------------- causal flash attention (r14 structure) --------------------
__global__ __launch_bounds__(64) void ca_attn(
    const unsigned short* __restrict__ q, const unsigned short* __restrict__ kfl,
    const unsigned short* __restrict__ vfl, unsigned short* __restrict__ y) {
  __shared__ uint32_t els[32][33];
  int l = threadIdx.x & 63;
  int bh = blockIdx.x;                              // XCD = id%8 = bh%8 -> KV L2-pinned
  int qt = (int)gridDim.y - 1 - (int)blockIdx.y;    // heavy q-tiles first
  int b = bh >> 4, h16 = bh & 15;
  const unsigned short* qp = q + (size_t)b * Tx * Cx + h16 * Dx;
  const unsigned short* kb = kfl + (size_t)bh * 64 * 2048 + l * 8;
  const unsigned short* vb = vfl + (size_t)bh * 64 * 2048 + l * 8;
  int lo = l & 31, hi = l >> 5;
  constexpr float SHIFT = 20.0f;  // static softmax shift (log2 domain)
  const uint32_t one2 = 0x3F803F80u;  // bf16 1.0 x2
  uint4 onesw{one2, one2, one2, one2};
  bf16x8 ONES = __builtin_bit_cast(bf16x8, onesw);

  int qbase = qt * 32;

  bf16x8 qf[4];
  {
    const unsigned short* qr = qp + (size_t)(qbase + lo) * Cx + hi * 8;
#pragma unroll
    for (int c = 0; c < 4; ++c) qf[c] = *(const bf16x8*)(qr + c * 16);
  }

  f32x16 acc0 = {}, acc1 = {}, sacc = {};
  int nt = qt + 1;

  uint4 rk[4], rv[4];
  auto loadK = [&](int t) {
#pragma unroll
    for (int c = 0; c < 4; ++c) rk[c] = *(const uint4*)(kb + t * 2048 + c * 512);
  };
  auto loadV = [&](int t) {
#pragma unroll
    for (int j = 0; j < 4; ++j) rv[j] = *(const uint4*)(vb + t * 2048 + j * 512);
  };
  loadK(0);
  loadV(0);

  for (int t = 0; t < nt; ++t) {
    bf16x8 kf[4], vf[4];
#pragma unroll
    for (int c = 0; c < 4; ++c) kf[c] = __builtin_bit_cast(bf16x8, rk[c]);
#pragma unroll
    for (int c = 0; c < 4; ++c) vf[c] = __builtin_bit_cast(bf16x8, rv[c]);
    if (t + 1 < nt) { loadK(t + 1); loadV(t + 1); }  // prefetch under softmax

    __builtin_amdgcn_s_setprio(1);
    f32x16 s = {};
    s = __builtin_amdgcn_mfma_f32_32x32x16_bf16(kf[0], qf[0], s, 0, 0, 0);
    s = __builtin_amdgcn_mfma_f32_32x32x16_bf16(kf[1], qf[1], s, 0, 0, 0);
    s = __builtin_amdgcn_mfma_f32_32x32x16_bf16(kf[2], qf[2], s, 0, 0, 0);
    s = __builtin_amdgcn_mfma_f32_32x32x16_bf16(kf[3], qf[3], s, 0, 0, 0);
    __builtin_amdgcn_s_setprio(0);

    float p[16];
    if (t == nt - 1) {  // diagonal tile is exactly the last tile
#pragma unroll
      for (int r = 0; r < 16; ++r) {
        int kvr = (r & 3) + 8 * (r >> 2) + 4 * hi;
        p[r] = (kvr > lo) ? 0.f : exp2f(s[r] - SHIFT);
      }
    } else {
#pragma unroll
      for (int r = 0; r < 16; ++r) p[r] = exp2f(s[r] - SHIFT);
    }

    uint32_t pk[8];
#pragma unroll
    for (int i = 0; i < 8; ++i) pk[i] = pkbf(p[2 * i], p[2 * i + 1]);
    pl32swap(pk[0], pk[2]);
    pl32swap(pk[1], pk[3]);
    pl32swap(pk[4], pk[6]);
    pl32swap(pk[5], pk[7]);
    uint4 xw{pk[0], pk[1], pk[2], pk[3]}, yw{pk[4], pk[5], pk[6], pk[7]};
    bf16x8 PB0 = __builtin_bit_cast(bf16x8, xw);
    bf16x8 PB1 = __builtin_bit_cast(bf16x8, yw);
    __builtin_amdgcn_s_setprio(1);
    acc0 = __builtin_amdgcn_mfma_f32_32x32x16_bf16(vf[0], PB0, acc0, 0, 0, 0);
    acc1 = __builtin_amdgcn_mfma_f32_32x32x16_bf16(vf[2], PB0, acc1, 0, 0, 0);
    sacc = __builtin_amdgcn_mfma_f32_32x32x16_bf16(ONES, PB0, sacc, 0, 0, 0);
    acc0 = __builtin_amdgcn_mfma_f32_32x32x16_bf16(vf[1], PB1, acc0, 0, 0, 0);
    acc1 = __builtin_amdgcn_mfma_f32_32x32x16_bf16(vf[3], PB1, acc1, 0, 0, 0);
    sacc = __builtin_amdgcn_mfma_f32_32x32x16_bf16(ONES, PB1, sacc, 0, 0, 0);
    __builtin_amdgcn_s_setprio(0);
  }

  float rl = __builtin_amdgcn_rcpf(sacc[0]);  // lsum for this lane's q-col
#pragma unroll
  for (int dc = 0; dc < 2; ++dc) {
    f32x16 a = dc ? acc1 : acc0;
#pragma unroll
    for (int i = 0; i < 8; ++i) {
      uint32_t pkd = pkbf(a[2 * i] * rl, a[2 * i + 1] * rl);
      int d2 = (i & 1) + 4 * (i >> 1) + 2 * hi + dc * 16;
      els[lo][d2] = pkd;
    }
  }
  __syncthreads();
  unsigned short* yp = y + (size_t)b * Tx * Cx + h16 * Dx;
#pragma unroll
  for (int pp = 0; pp < 16; ++pp) {
    int qr = 2 * pp + hi;
    uint32_t val = els[qr][lo];
    *(uint32_t*)(yp + (size_t)(qbase + qr) * Cx + lo * 2) = val;
  }
}

}  // namespace

extern "C" void kernel_launch(void* const* d_in, const int* in_sizes, int n_in,
                              void* d_out, int out_size, void* d_ws, size_t ws_size,
                              hipStream_t stream) {
  const float* x = (const float*)d_in[0];
  const float* Wq = (const float*)d_in[1];
  const float* bq = (const float*)d_in[2];
  const float* Wk = (const float*)d_in[3];
  const float* bk = (const float*)d_in[4];
  const float* Wv = (const float*)d_in[5];
  const float* bv = (const float*)d_in[6];
  const float* Wp = (const float*)d_in[7];
  const float* bp = (const float*)d_in[8];

  unsigned short* xb = (unsigned short*)d_ws;                 // 8192*1024
  unsigned short* wt = xb + (size_t)Mx * Cx;                  // 4 * 1024*1024 (WqT,WkT,WvT,WpT)
  float* ct = (float*)(wt + (size_t)4 * Cx * Cx);             // 2048*32
  float* st = ct + Tx * 32;
  unsigned short* qb = (unsigned short*)(st + Tx * 32);       // q (gemm0 out)
  unsigned short* yb = qb + (size_t)Mx * Cx;                  // attn out
  unsigned short* kfl = yb + (size_t)Mx * Cx;                 // 64*64*2048 = 8M ushort
  unsigned short* vfl = kfl + (size_t)64 * 64 * 2048;

  ca_cvt<<<dim3(2048), dim3(256), 0, stream>>>(x, xb, Mx * Cx / 4);
  ca_wt4<<<dim3(32, 32, 4), dim3(256), 0, stream>>>(Wq, Wk, Wv, Wp, wt);
  ca_rtab<<<dim3(Tx * 32 / 256), dim3(256), 0, stream>>>(ct, st);

  ca_gemm<0><<<dim3(64, 24), dim3(256), 0, stream>>>(
      /*A=*/xb, /*Bt=*/wt, /*b0=*/bq, /*b1=*/bk, /*b2=*/bv,
      /*ctab=*/ct, /*stab=*/st, /*out=*/qb, /*kfl=*/kfl, /*vfl=*/vfl,
      /*M=*/Mx, /*N=*/3072, /*K=*/Cx);
  ca_attn<<<dim3(64, 64), dim3(64), 0, stream>>>(qb, kfl, vfl, yb);
  ca_gemm<1><<<dim3(64, 8), dim3(256), 0, stream>>>(
      /*A=*/yb, /*Bt=*/wt + (size_t)3 * Cx * Cx, /*b0=*/bp, /*b1=*/nullptr, /*b2=*/nullptr,
      /*ctab=*/nullptr, /*stab=*/nullptr, /*out=*/d_out, /*kfl=*/nullptr, /*vfl=*/nullptr,
      /*M=*/Mx, /*N=*/Cx, /*K=*/Cx);
}

// Round 23
// 201.609 us; speedup vs baseline: 1.0549x; 1.0157x over previous
//
#include <hip/hip_runtime.h>
#include <hip/hip_bf16.h>
#include <stdint.h>

namespace {

constexpr int Bx = 4, Tx = 2048, Cx = 1024, Hx = 16, Dx = 64;
constexpr int Mx = Bx * Tx;  // 8192

typedef __attribute__((ext_vector_type(8))) short bf16x8;
typedef __attribute__((ext_vector_type(4))) float f32x4;
typedef __attribute__((ext_vector_type(16))) float f32x16;
typedef __attribute__((ext_vector_type(2))) unsigned int u32x2;

__device__ __forceinline__ float b2f(unsigned short u) {
  unsigned int v = ((unsigned int)u) << 16;
  return __builtin_bit_cast(float, v);
}
__device__ __forceinline__ unsigned short f2b(float f) {
  unsigned int v = __builtin_bit_cast(unsigned int, f);
  v += 0x7fffu + ((v >> 16) & 1u);
  return (unsigned short)(v >> 16);
}
__device__ __forceinline__ uint32_t pkbf(float a, float b) {
  __hip_bfloat162 h = __float22bfloat162_rn(float2{a, b});
  uint32_t r;
  __builtin_memcpy(&r, &h, 4);  // __hip_bfloat162 not trivially copyable -> no bit_cast
  return r;
}
// permlane32_swap via builtin (compiler handles VALU->permlane hazards):
//   a_new[i] = i<32 ? a[i] : b[i-32];  b_new[i] = i<32 ? a[i+32] : b[i]
__device__ __forceinline__ void pl32swap(uint32_t& a, uint32_t& b) {
  u32x2 r = __builtin_amdgcn_permlane32_swap(a, b, false, false);
  a = r[0];
  b = r[1];
}

#define GLD16(g, lp) __builtin_amdgcn_global_load_lds(                     \
    (__attribute__((address_space(1))) void*)(g),                          \
    (__attribute__((address_space(3))) void*)(lp), 16, 0, 0)

// ---------------- convert fp32 -> bf16 (vectorized) ----------------
__global__ void ca_cvt(const float* __restrict__ src, unsigned short* __restrict__ dst, int n4) {
  int i = blockIdx.x * blockDim.x + threadIdx.x;
  int stride = gridDim.x * blockDim.x;
  for (; i < n4; i += stride) {
    float4 f = ((const float4*)src)[i];
    ushort4 o;
    o.x = f2b(f.x); o.y = f2b(f.y); o.z = f2b(f.z); o.w = f2b(f.w);
    ((ushort4*)dst)[i] = o;
  }
}

// ---------------- 4x W (K x N) -> Wt (N x K) bf16, one launch ---------------
__global__ void ca_wt4(const float* __restrict__ W0, const float* __restrict__ W1,
                       const float* __restrict__ W2, const float* __restrict__ W3,
                       unsigned short* __restrict__ Wt) {
  __shared__ float tile[32][33];
  int z = blockIdx.z;
  const float* W = z == 0 ? W0 : (z == 1 ? W1 : (z == 2 ? W2 : W3));
  unsigned short* o = Wt + (size_t)z * Cx * Cx;
  int n0 = blockIdx.x * 32, k0 = blockIdx.y * 32;
  int j = threadIdx.x & 31, i = threadIdx.x >> 5;  // i in 0..7
#pragma unroll
  for (int r = 0; r < 4; ++r)
    tile[i + 8 * r][j] = W[(size_t)(k0 + i + 8 * r) * Cx + n0 + j];
  __syncthreads();
#pragma unroll
  for (int r = 0; r < 4; ++r)
    o[(size_t)(n0 + i + 8 * r) * Cx + k0 + j] = f2b(tile[j][i + 8 * r]);
}

// ---------------- RoPE cos/sin table ----------------
__global__ void ca_rtab(float* __restrict__ ct, float* __restrict__ st) {
  int idx = blockIdx.x * blockDim.x + threadIdx.x;  // < Tx*32
  int t = idx >> 5, i = idx & 31;
  float fr = expf((float)i * -0.29710775393471563f);  // -ln(10000)/31
  float a = (float)t * fr;
  ct[idx] = cosf(a);
  st[idx] = sinf(a);
}

// ---------------- GEMM: A (MxK bf16) x Bt (NxK bf16) + bias ----------------
// r20 2-phase structure (confirmed optimum of its family by r15/r19/r21).
// MODE 0 epilogue: q row-major + k,v direct to fragment-linear + fused RoPE.
template <int MODE>
__global__ __launch_bounds__(256) void ca_gemm(
    const unsigned short* __restrict__ A, const unsigned short* __restrict__ Bt,
    const float* __restrict__ b0, const float* __restrict__ b1, const float* __restrict__ b2,
    const float* __restrict__ ctab, const float* __restrict__ stab,
    void* __restrict__ out, unsigned short* __restrict__ kfl, unsigned short* __restrict__ vfl,
    int M, int N, int K) {
  __shared__ __align__(16) unsigned short Al[2][128 * 32];
  __shared__ __align__(16) unsigned short Bl[2][128 * 32];
  int tid = threadIdx.x;
  int w = tid >> 6, l = tid & 63;
  int m0 = blockIdx.x * 128, n0 = blockIdx.y * 128;  // m-fast (r16 order)
  int wm = (w >> 1) * 64, wn = (w & 1) * 64;
  f32x4 acc[4][4] = {};

  int lr = l & 15, lk8 = (l >> 4) * 8;
  int srow = w * 32 + (l >> 2), scol = (l & 3) * 8;
  const unsigned short* ga0 = A + (size_t)(m0 + srow) * K + scol;
  const unsigned short* gb0 = Bt + (size_t)(n0 + srow) * K + scol;
  int nk = K / 32;
  auto stage = [&](int kt, int buf) {
    const unsigned short* ga = ga0 + kt * 32;
    const unsigned short* gb = gb0 + kt * 32;
    unsigned short* la = &Al[buf][w * 1024];
    unsigned short* lb = &Bl[buf][w * 1024];
    GLD16(ga, la);
    GLD16(ga + (size_t)16 * K, la + 512);
    GLD16(gb, lb);
    GLD16(gb + (size_t)16 * K, lb + 512);
  };
  stage(0, 0);
  __syncthreads();  // buf0 ready
  int cur = 0;
  for (int kt = 0; kt < nk; ++kt) {
    if (kt + 1 < nk) stage(kt + 1, cur ^ 1);  // in flight under compute
    bf16x8 af[4], bfr[4];
#pragma unroll
    for (int mi = 0; mi < 4; ++mi)
      af[mi] = *(const bf16x8*)&Al[cur][(wm + mi * 16 + lr) * 32 + lk8];
#pragma unroll
    for (int ni = 0; ni < 4; ++ni)
      bfr[ni] = *(const bf16x8*)&Bl[cur][(wn + ni * 16 + lr) * 32 + lk8];
#pragma unroll
    for (int mi = 0; mi < 4; ++mi)
#pragma unroll
      for (int ni = 0; ni < 4; ++ni)
        acc[mi][ni] = __builtin_amdgcn_mfma_f32_16x16x32_bf16(af[mi], bfr[ni], acc[mi][ni], 0, 0, 0);
    __syncthreads();  // drains stage (vmcnt0) + all waves done reading cur
    cur ^= 1;
  }

  int lq4 = (l >> 4) * 4;
  if (MODE == 0) {
    constexpr float SC = 0.18033688011112042f;  // 0.125 * log2(e)
    int which = n0 >> 10;
    int nb = n0 & 1023;
    const float* bias = which == 0 ? b0 : (which == 1 ? b1 : b2);
    unsigned short* o = (unsigned short*)out;  // q only
    bool doRope = which < 2;
    float scl = which == 0 ? SC : 1.0f;
#pragma unroll
    for (int mi = 0; mi < 4; ++mi)
#pragma unroll
      for (int ni = 0; ni < 4; ++ni) {
        int ncol = nb + wn + ni * 16 + lr;
        float bv = bias[ncol];
        int j = (ncol & 63) >> 1;
        bool even = (ncol & 1) == 0;
        int h = ncol >> 6, d = ncol & 63;
        int m_base = m0 + wm + mi * 16 + lq4;
        float vals[4];
#pragma unroll
        for (int rg = 0; rg < 4; ++rg) {
          int m = m_base + rg;
          float val = acc[mi][ni][rg] + bv;
          if (doRope) {
            int t = m & (Tx - 1);
            float c = ctab[t * 32 + j], s = stab[t * 32 + j];
            float other = __shfl_xor(val, 1);
            float res = even ? (val * c - other * s) : (other * s + val * c);
            val = res * scl;
          }
          vals[rg] = val;
        }
        if (which == 0) {
#pragma unroll
          for (int rg = 0; rg < 4; ++rg)
            o[(size_t)(m_base + rg) * 1024 + ncol] = f2b(vals[rg]);
        } else if (which == 1) {
          // k -> fragment-linear: [bh][t>>5][d>>4][((d>>3)&1)*32+(t&31)]*8+(d&7)
          int bh = (m_base >> 11) * 16 + h;
          size_t tilebase = ((size_t)bh * 64) * 2048 + (d >> 4) * 512 + (((d >> 3) & 1) * 32) * 8 + (d & 7);
#pragma unroll
          for (int rg = 0; rg < 4; ++rg) {
            int t = (m_base + rg) & (Tx - 1);
            kfl[tilebase + (size_t)(t >> 5) * 2048 + (t & 31) * 8] = f2b(vals[rg]);
          }
        } else {
          // v -> fragment-linear: rg-consecutive t => consecutive e: one 8B store
          int t = m_base & (Tx - 1);
          int bh = (m_base >> 11) * 16 + h;
          int tin = t & 31;
          size_t base = ((size_t)bh * 64 + (t >> 5)) * 2048 +
                        ((d >> 5) * 2 + ((tin >> 4) & 1)) * 512 +
                        (((tin >> 3) & 1) * 32 + (d & 31)) * 8 + (tin & 7);
          ushort4 pk4;
          pk4.x = f2b(vals[0]); pk4.y = f2b(vals[1]);
          pk4.z = f2b(vals[2]); pk4.w = f2b(vals[3]);
          *(ushort4*)(vfl + base) = pk4;
        }
      }
  } else {
    float* o = (float*)out;
#pragma unroll
    for (int mi = 0; mi < 4; ++mi)
#pragma unroll
      for (int ni = 0; ni < 4; ++ni) {
        int ncol = n0 + wn + ni * 16 + lr;
        float bv = b0[ncol];
#pragma unroll
        for (int rg = 0; rg < 4; ++rg) {
          int m = m0 + wm + mi * 16 + lq4 + rg;
          o[(size_t)m * N + ncol] = acc[mi][ni][rg] + bv;
        }
      }
  }
}

// ---------------- causal flash attention, 2x kv-tile unroll -----------------
// r23: since r11's static-max softmax removed ALL online state (no m/l
// rescale), kv-tiles are fully independent -> a 2-tile unroll gives
// cross-tile ILP (QK(t+1) MFMA chain overlaps softmax(t) VALU/trans) with
// only +32 VGPR for the second rk/rv set -- unlike r9's dual-chain which
// needed duplicated softmax state (200 VGPR, occupancy cliff).
__global__ __launch_bounds__(64) void ca_attn(
    const unsigned short* __restrict__ q, const unsigned short* __restrict__ kfl,
    const unsigned short* __restrict__ vfl, unsigned short* __restrict__ y) {
  __shared__ uint32_t els[32][33];
  int l = threadIdx.x & 63;
  int bh = blockIdx.x;                              // XCD = id%8 = bh%8 -> KV L2-pinned
  int qt = (int)gridDim.y - 1 - (int)blockIdx.y;    // heavy q-tiles first
  int b = bh >> 4, h16 = bh & 15;
  const unsigned short* qp = q + (size_t)b * Tx * Cx + h16 * Dx;
  const unsigned short* kb = kfl + (size_t)bh * 64 * 2048 + l * 8;
  const unsigned short* vb = vfl + (size_t)bh * 64 * 2048 + l * 8;
  int lo = l & 31, hi = l >> 5;
  constexpr float SHIFT = 20.0f;  // static softmax shift (log2 domain)
  const uint32_t one2 = 0x3F803F80u;  // bf16 1.0 x2
  uint4 onesw{one2, one2, one2, one2};
  bf16x8 ONES = __builtin_bit_cast(bf16x8, onesw);

  int qbase = qt * 32;

  bf16x8 qf[4];
  {
    const unsigned short* qr = qp + (size_t)(qbase + lo) * Cx + hi * 8;
#pragma unroll
    for (int c = 0; c < 4; ++c) qf[c] = *(const bf16x8*)(qr + c * 16);
  }

  f32x16 acc0 = {}, acc1 = {}, sacc = {};
  int nt = qt + 1;

  uint4 rk1[4], rv1[4], rk2[4], rv2[4];
  auto loadK = [&](uint4* rk, int t) {
#pragma unroll
    for (int c = 0; c < 4; ++c) rk[c] = *(const uint4*)(kb + t * 2048 + c * 512);
  };
  auto loadV = [&](uint4* rv, int t) {
#pragma unroll
    for (int j = 0; j < 4; ++j) rv[j] = *(const uint4*)(vb + t * 2048 + j * 512);
  };

  // one full tile: QK -> static-shift softmax -> pack -> PV(+lsum via MFMA)
  auto tileStep = [&](const uint4* rk, const uint4* rv, bool diag) {
    bf16x8 kf[4], vf[4];
#pragma unroll
    for (int c = 0; c < 4; ++c) kf[c] = __builtin_bit_cast(bf16x8, rk[c]);
#pragma unroll
    for (int c = 0; c < 4; ++c) vf[c] = __builtin_bit_cast(bf16x8, rv[c]);
    __builtin_amdgcn_s_setprio(1);
    f32x16 s = {};
    s = __builtin_amdgcn_mfma_f32_32x32x16_bf16(kf[0], qf[0], s, 0, 0, 0);
    s = __builtin_amdgcn_mfma_f32_32x32x16_bf16(kf[1], qf[1], s, 0, 0, 0);
    s = __builtin_amdgcn_mfma_f32_32x32x16_bf16(kf[2], qf[2], s, 0, 0, 0);
    s = __builtin_amdgcn_mfma_f32_32x32x16_bf16(kf[3], qf[3], s, 0, 0, 0);
    __builtin_amdgcn_s_setprio(0);
    float p[16];
    if (diag) {
#pragma unroll
      for (int r = 0; r < 16; ++r) {
        int kvr = (r & 3) + 8 * (r >> 2) + 4 * hi;
        p[r] = (kvr > lo) ? 0.f : exp2f(s[r] - SHIFT);
      }
    } else {
#pragma unroll
      for (int r = 0; r < 16; ++r) p[r] = exp2f(s[r] - SHIFT);
    }
    uint32_t pk[8];
#pragma unroll
    for (int i = 0; i < 8; ++i) pk[i] = pkbf(p[2 * i], p[2 * i + 1]);
    pl32swap(pk[0], pk[2]);
    pl32swap(pk[1], pk[3]);
    pl32swap(pk[4], pk[6]);
    pl32swap(pk[5], pk[7]);
    uint4 xw{pk[0], pk[1], pk[2], pk[3]}, yw{pk[4], pk[5], pk[6], pk[7]};
    bf16x8 PB0 = __builtin_bit_cast(bf16x8, xw);
    bf16x8 PB1 = __builtin_bit_cast(bf16x8, yw);
    __builtin_amdgcn_s_setprio(1);
    acc0 = __builtin_amdgcn_mfma_f32_32x32x16_bf16(vf[0], PB0, acc0, 0, 0, 0);
    acc1 = __builtin_amdgcn_mfma_f32_32x32x16_bf16(vf[2], PB0, acc1, 0, 0, 0);
    sacc = __builtin_amdgcn_mfma_f32_32x32x16_bf16(ONES, PB0, sacc, 0, 0, 0);
    acc0 = __builtin_amdgcn_mfma_f32_32x32x16_bf16(vf[1], PB1, acc0, 0, 0, 0);
    acc1 = __builtin_amdgcn_mfma_f32_32x32x16_bf16(vf[3], PB1, acc1, 0, 0, 0);
    sacc = __builtin_amdgcn_mfma_f32_32x32x16_bf16(ONES, PB1, sacc, 0, 0, 0);
    __builtin_amdgcn_s_setprio(0);
  };

  loadK(rk1, 0);
  loadV(rv1, 0);
  int t = 0;
  for (; t + 1 < nt; t += 2) {
    loadK(rk2, t + 1);              // tile t+1 loads issued before tile t compute
    loadV(rv2, t + 1);
    tileStep(rk1, rv1, false);      // first of pair: never the diagonal tile
    if (t + 2 < nt) { loadK(rk1, t + 2); loadV(rv1, t + 2); }
    tileStep(rk2, rv2, t + 1 == nt - 1);
  }
  if (t < nt) tileStep(rk1, rv1, true);  // odd tail == diagonal tile

  float rl = __builtin_amdgcn_rcpf(sacc[0]);  // lsum for this lane's q-col
#pragma unroll
  for (int dc = 0; dc < 2; ++dc) {
    f32x16 a = dc ? acc1 : acc0;
#pragma unroll
    for (int i = 0; i < 8; ++i) {
      uint32_t pkd = pkbf(a[2 * i] * rl, a[2 * i + 1] * rl);
      int d2 = (i & 1) + 4 * (i >> 1) + 2 * hi + dc * 16;
      els[lo][d2] = pkd;
    }
  }
  __syncthreads();
  unsigned short* yp = y + (size_t)b * Tx * Cx + h16 * Dx;
#pragma unroll
  for (int pp = 0; pp < 16; ++pp) {
    int qr = 2 * pp + hi;
    uint32_t val = els[qr][lo];
    *(uint32_t*)(yp + (size_t)(qbase + qr) * Cx + lo * 2) = val;
  }
}

}  // namespace

extern "C" void kernel_launch(void* const* d_in, const int* in_sizes, int n_in,
                              void* d_out, int out_size, void* d_ws, size_t ws_size,
                              hipStream_t stream) {
  const float* x = (const float*)d_in[0];
  const float* Wq = (const float*)d_in[1];
  const float* bq = (const float*)d_in[2];
  const float* Wk = (const float*)d_in[3];
  const float* bk = (const float*)d_in[4];
  const float* Wv = (const float*)d_in[5];
  const float* bv = (const float*)d_in[6];
  const float* Wp = (const float*)d_in[7];
  const float* bp = (const float*)d_in[8];

  unsigned short* xb = (unsigned short*)d_ws;                 // 8192*1024
  unsigned short* wt = xb + (size_t)Mx * Cx;                  // 4 * 1024*1024 (WqT,WkT,WvT,WpT)
  float* ct = (float*)(wt + (size_t)4 * Cx * Cx);             // 2048*32
  float* st = ct + Tx * 32;
  unsigned short* qb = (unsigned short*)(st + Tx * 32);       // q (gemm0 out)
  unsigned short* yb = qb + (size_t)Mx * Cx;                  // attn out
  unsigned short* kfl = yb + (size_t)Mx * Cx;                 // 64*64*2048 = 8M ushort
  unsigned short* vfl = kfl + (size_t)64 * 64 * 2048;

  ca_cvt<<<dim3(2048), dim3(256), 0, stream>>>(x, xb, Mx * Cx / 4);
  ca_wt4<<<dim3(32, 32, 4), dim3(256), 0, stream>>>(Wq, Wk, Wv, Wp, wt);
  ca_rtab<<<dim3(Tx * 32 / 256), dim3(256), 0, stream>>>(ct, st);

  ca_gemm<0><<<dim3(64, 24), dim3(256), 0, stream>>>(
      /*A=*/xb, /*Bt=*/wt, /*b0=*/bq, /*b1=*/bk, /*b2=*/bv,
      /*ctab=*/ct, /*stab=*/st, /*out=*/qb, /*kfl=*/kfl, /*vfl=*/vfl,
      /*M=*/Mx, /*N=*/3072, /*K=*/Cx);
  ca_attn<<<dim3(64, 64), dim3(64), 0, stream>>>(qb, kfl, vfl, yb);
  ca_gemm<1><<<dim3(64, 8), dim3(256), 0, stream>>>(
      /*A=*/yb, /*Bt=*/wt + (size_t)3 * Cx * Cx, /*b0=*/bp, /*b1=*/nullptr, /*b2=*/nullptr,
      /*ctab=*/nullptr, /*stab=*/nullptr, /*out=*/d_out, /*kfl=*/nullptr, /*vfl=*/nullptr,
      /*M=*/Mx, /*N=*/Cx, /*K=*/Cx);
}